// Round 2
// baseline (1945.234 us; speedup 1.0000x reference)
//
#include <hip/hip_runtime.h>
#include <hip/hip_bf16.h>

#define BN 32
#define CC 128
#define NN 2025
#define KK 9
#define NGROUP 4
#define CPG 32
#define GN_EPS 1e-5f
#define ROWS_TOTAL (BN * NN)   // 64800

// ---------------- Kernel 1: L2 normalize; write xn [B*N][C] and xnT [B][C][N] ----------------
__global__ __launch_bounds__(256) void k_normalize(const float* __restrict__ x,
                                                   float* __restrict__ xn,
                                                   float* __restrict__ xnT) {
    int wid  = blockIdx.x * 4 + (threadIdx.x >> 6);   // one wave per (b,n)
    int lane = threadIdx.x & 63;
    int b = wid / NN;
    int n = wid - b * NN;
    int c0 = lane, c1 = lane + 64;
    float v0 = x[(b * CC + c0) * NN + n];
    float v1 = x[(b * CC + c1) * NN + n];
    float ss = v0 * v0 + v1 * v1;
#pragma unroll
    for (int off = 32; off > 0; off >>= 1) ss += __shfl_xor(ss, off);
    float nrm = sqrtf(ss);
    float s = 1.0f / fmaxf(nrm, 1e-12f);
    v0 *= s; v1 *= s;
    xn[wid * CC + c0] = v0;
    xn[wid * CC + c1] = v1;
    xnT[(b * CC + c0) * NN + n] = v0;
    xnT[(b * CC + c1) * NN + n] = v1;
}

// ---------------- Kernel 2: fused sim + top-k ----------------
// Block: 64 rows x full N columns (chunks of 64). thread = (tr 0..15)x(tm 0..15),
// each thread owns a 4x4 (row x m) accumulator tile. Per-thread top-9 lists per row,
// merged across the 16 m-threads per row via LDS at the end.
#define RT 64
#define MCH 64
__global__ __launch_bounds__(256) void k_sim_topk(const float* __restrict__ xnT,
                                                  float* __restrict__ vout,
                                                  int* __restrict__ iout) {
    __shared__ float lds[16384];          // 64 KB: rowsAT [128][64] | colBT [128][64]
    float* rowsAT = lds;
    float* colBT  = lds + 8192;

    int b  = blockIdx.y;
    int r0 = blockIdx.x * RT;
    int t  = threadIdx.x;
    int tr = t & 15, tm = t >> 4;

    // stage rowsAT[c][r] from xnT (coalesced along r)
    for (int it = 0; it < 32; ++it) {
        int q = t + it * 256;
        int rr = q & 63, c = q >> 6;
        int r = r0 + rr;
        rowsAT[c * 64 + rr] = (r < NN) ? xnT[(b * CC + c) * NN + r] : 0.0f;
    }

    float val9[4][9]; int idx9[4][9];
    float minv[4]; int minp[4];
#pragma unroll
    for (int ri = 0; ri < 4; ++ri) {
#pragma unroll
        for (int k = 0; k < 9; ++k) { val9[ri][k] = -3.0e38f; idx9[ri][k] = 0x7fffffff; }
        minv[ri] = -3.0e38f; minp[ri] = 0;
    }

    for (int m0 = 0; m0 < NN; m0 += MCH) {
        __syncthreads();
        for (int it = 0; it < 32; ++it) {
            int q = t + it * 256;
            int mm = q & 63, c = q >> 6;
            int m = m0 + mm;
            colBT[c * 64 + mm] = (m < NN) ? xnT[(b * CC + c) * NN + m] : 0.0f;
        }
        __syncthreads();

        float acc[4][4];
#pragma unroll
        for (int i = 0; i < 4; ++i)
#pragma unroll
            for (int j = 0; j < 4; ++j) acc[i][j] = 0.0f;

        for (int c = 0; c < CC; ++c) {
            float4 av = *(const float4*)&rowsAT[c * 64 + 4 * tr];
            float4 bv = *(const float4*)&colBT[c * 64 + 4 * tm];
            acc[0][0] += av.x * bv.x; acc[0][1] += av.x * bv.y; acc[0][2] += av.x * bv.z; acc[0][3] += av.x * bv.w;
            acc[1][0] += av.y * bv.x; acc[1][1] += av.y * bv.y; acc[1][2] += av.y * bv.z; acc[1][3] += av.y * bv.w;
            acc[2][0] += av.z * bv.x; acc[2][1] += av.z * bv.y; acc[2][2] += av.z * bv.z; acc[2][3] += av.z * bv.w;
            acc[3][0] += av.w * bv.x; acc[3][1] += av.w * bv.y; acc[3][2] += av.w * bv.z; acc[3][3] += av.w * bv.w;
        }

        // push candidates; within a thread m strictly ascends, so strict '>' keeps
        // the smaller index on value ties (jax top_k tie rule).
#pragma unroll
        for (int mi = 0; mi < 4; ++mi) {
            int m = m0 + 4 * tm + mi;
            bool ok = (m < NN);
#pragma unroll
            for (int ri = 0; ri < 4; ++ri) {
                float cand = acc[ri][mi];
                if (ok && cand > minv[ri]) {
                    int p = minp[ri];
#pragma unroll
                    for (int k = 0; k < 9; ++k) if (k == p) { val9[ri][k] = cand; idx9[ri][k] = m; }
                    // rescan for new worst (min value; ties -> larger index is worse)
                    float mv = val9[ri][0]; int mvp = 0; int mvi = idx9[ri][0];
#pragma unroll
                    for (int k = 1; k < 9; ++k) {
                        if (val9[ri][k] < mv || (val9[ri][k] == mv && idx9[ri][k] > mvi)) {
                            mv = val9[ri][k]; mvi = idx9[ri][k]; mvp = k;
                        }
                    }
                    minv[ri] = mv; minp[ri] = mvp;
                }
            }
        }
    }

    __syncthreads();
    // merge 16 lists per row; two passes of 32 rows to fit LDS overlay
    float* mv = lds;                       // [32*144] values
    int*   mi = (int*)(lds + 4608);        // [32*144] indices
    for (int p = 0; p < 2; ++p) {
        if ((tr >> 3) == p) {
#pragma unroll
            for (int ri = 0; ri < 4; ++ri) {
                int rl = (tr & 7) * 4 + ri;       // 0..31
#pragma unroll
                for (int k = 0; k < 9; ++k) {
                    mv[(rl * 16 + tm) * 9 + k] = val9[ri][k];
                    mi[(rl * 16 + tm) * 9 + k] = idx9[ri][k];
                }
            }
        }
        __syncthreads();
        if (t < 32) {
            int r = r0 + p * 32 + t;
            if (r < NN) {
                float tv[9]; int ti[9];
#pragma unroll
                for (int k = 0; k < 9; ++k) { tv[k] = -3.0e38f; ti[k] = 0x7fffffff; }
                float wv = -3.0e38f; int wi = 0x7fffffff; int wp = 0;
                for (int j = 0; j < 144; ++j) {
                    float cv = mv[t * 144 + j]; int ci = mi[t * 144 + j];
                    if (cv > wv || (cv == wv && ci < wi)) {
#pragma unroll
                        for (int k = 0; k < 9; ++k) if (k == wp) { tv[k] = cv; ti[k] = ci; }
                        wv = tv[0]; wi = ti[0]; wp = 0;
#pragma unroll
                        for (int k = 1; k < 9; ++k) {
                            if (tv[k] < wv || (tv[k] == wv && ti[k] > wi)) { wv = tv[k]; wi = ti[k]; wp = k; }
                        }
                    }
                }
                float s = 1e-6f;
#pragma unroll
                for (int k = 0; k < 9; ++k) s += tv[k];
                float inv = 1.0f / s;
                int base = (b * NN + r) * KK;
#pragma unroll
                for (int k = 0; k < 9; ++k) {
                    vout[base + k] = tv[k] * inv;
                    iout[base + k] = ti[k];
                }
            }
        }
        __syncthreads();
    }
}

// ---------------- Kernel 3: GEMM out[64800][128] = in[64800][128] @ w[128][128] ----------------
// 32 rows per block; A-tile staged in LDS [c][r] with stride 36 (16B-aligned float4,
// breaks the worst bank conflicts); w read from global (coalesced, L2-hot 64 KB).
#define RST 36
__global__ __launch_bounds__(256) void k_gemm(const float* __restrict__ in,
                                              const float* __restrict__ w,
                                              float* __restrict__ out) {
    __shared__ float rowsT[CC * RST];    // 18 KB
    int t = threadIdx.x;
    int row0 = blockIdx.x * 32;

    // stage: q = (r,c), c innermost -> coalesced global reads
    for (int it = 0; it < 16; ++it) {
        int q = t + it * 256;
        int c = q & 127, r = q >> 7;
        rowsT[c * RST + r] = in[(row0 + r) * CC + c];
    }
    __syncthreads();

    int j = t & 127, half = t >> 7;
    float acc[16];
#pragma unroll
    for (int r = 0; r < 16; ++r) acc[r] = 0.0f;

    for (int c = 0; c < CC; ++c) {
        float wv = w[c * CC + j];
        const float4* ap = (const float4*)&rowsT[c * RST + half * 16];
        float4 a0 = ap[0], a1 = ap[1], a2 = ap[2], a3 = ap[3];
        acc[0]  += a0.x * wv; acc[1]  += a0.y * wv; acc[2]  += a0.z * wv; acc[3]  += a0.w * wv;
        acc[4]  += a1.x * wv; acc[5]  += a1.y * wv; acc[6]  += a1.z * wv; acc[7]  += a1.w * wv;
        acc[8]  += a2.x * wv; acc[9]  += a2.y * wv; acc[10] += a2.z * wv; acc[11] += a2.w * wv;
        acc[12] += a3.x * wv; acc[13] += a3.y * wv; acc[14] += a3.z * wv; acc[15] += a3.w * wv;
    }
#pragma unroll
    for (int r = 0; r < 16; ++r) {
        int row = row0 + half * 16 + r;
        out[row * CC + j] = acc[r];
    }
}

// ---------------- Kernel 4: gather + weighted sum + bias ----------------
__global__ __launch_bounds__(256) void k_gather(const float* __restrict__ xt,
                                                const float* __restrict__ v,
                                                const int* __restrict__ idx,
                                                const float* __restrict__ bias,
                                                float* __restrict__ out) {
    int t = threadIdx.x;
    int g = blockIdx.x * 2 + (t >> 7);
    int c = t & 127;
    if (g >= ROWS_TOTAL) return;
    int b = g / NN;
    int nb = b * NN;
    float acc = bias[c];
    int base = g * KK;
#pragma unroll
    for (int k = 0; k < KK; ++k) {
        int   ii = idx[base + k];
        float vv = v[base + k];
        acc += vv * xt[(nb + ii) * CC + c];
    }
    out[g * CC + c] = acc;
}

// ---------------- Kernel 5: GroupNorm stats per (b, group) ----------------
__global__ __launch_bounds__(256) void k_gnstats(const float* __restrict__ xin,
                                                 float* __restrict__ stats) {
    int bg = blockIdx.x; int b = bg >> 2; int gg = bg & 3;
    int base = b * (NN * CC) + gg * CPG;
    float s1 = 0.f, s2 = 0.f;
    for (int i = threadIdx.x; i < NN * CPG; i += 256) {
        float x = xin[base + (i >> 5) * CC + (i & 31)];
        s1 += x; s2 += x * x;
    }
#pragma unroll
    for (int off = 32; off > 0; off >>= 1) { s1 += __shfl_xor(s1, off); s2 += __shfl_xor(s2, off); }
    __shared__ float r1[4], r2[4];
    int w = threadIdx.x >> 6;
    if ((threadIdx.x & 63) == 0) { r1[w] = s1; r2[w] = s2; }
    __syncthreads();
    if (threadIdx.x == 0) {
        float a = r1[0] + r1[1] + r1[2] + r1[3];
        float q = r2[0] + r2[1] + r2[2] + r2[3];
        const float inv = 1.0f / (float)(NN * CPG);
        float mean = a * inv;
        float var = q * inv - mean * mean;
        stats[bg * 2]     = mean;
        stats[bg * 2 + 1] = rsqrtf(fmaxf(var, 0.f) + GN_EPS);
    }
}

// ---------------- Kernel 6: GN apply + SiLU (layout-preserving, fp32 out) ----------------
__global__ __launch_bounds__(256) void k_gnsilu(const float* __restrict__ xin,
                                                const float* __restrict__ stats,
                                                const float* __restrict__ gamma,
                                                const float* __restrict__ beta,
                                                float* __restrict__ out) {
    int e4 = (blockIdx.x * 256 + threadIdx.x) * 4;
    int c0 = e4 & 127;
    int b  = e4 / (NN * CC);
    int gg = c0 >> 5;
    float mean = stats[(b * 4 + gg) * 2];
    float rstd = stats[(b * 4 + gg) * 2 + 1];
    float4 x = *(const float4*)&xin[e4];
    float g0 = gamma[c0], g1 = gamma[c0 + 1], g2 = gamma[c0 + 2], g3 = gamma[c0 + 3];
    float p0 = beta[c0],  p1 = beta[c0 + 1],  p2 = beta[c0 + 2],  p3 = beta[c0 + 3];
    float y0 = (x.x - mean) * rstd * g0 + p0;
    float y1 = (x.y - mean) * rstd * g1 + p1;
    float y2 = (x.z - mean) * rstd * g2 + p2;
    float y3 = (x.w - mean) * rstd * g3 + p3;
    float4 r;
    r.x = y0 / (1.0f + expf(-y0));
    r.y = y1 / (1.0f + expf(-y1));
    r.z = y2 / (1.0f + expf(-y2));
    r.w = y3 / (1.0f + expf(-y3));
    *(float4*)&out[e4] = r;
}

// ---------------- Kernel 7: GN apply + SiLU + transpose to [B][C][N], fp32 out ----------------
__global__ __launch_bounds__(256) void k_gnsilu_out(const float* __restrict__ xin,
                                                    const float* __restrict__ stats,
                                                    const float* __restrict__ gamma,
                                                    const float* __restrict__ beta,
                                                    float* __restrict__ out) {
    __shared__ float tile[32 * 65];
    int b = blockIdx.z, ct = blockIdx.y, nt = blockIdx.x;
    int c0 = ct * 32, n0 = nt * 64;
    int t = threadIdx.x;
    int cj = t & 31, ni0 = t >> 5;
    int gg = c0 >> 5;
    float mean = stats[(b * 4 + gg) * 2];
    float rstd = stats[(b * 4 + gg) * 2 + 1];
    float gm = gamma[c0 + cj];
    float bt = beta[c0 + cj];
#pragma unroll
    for (int i = 0; i < 8; ++i) {
        int n = n0 + ni0 + i * 8;
        if (n < NN) {
            float x = xin[(b * NN + n) * CC + c0 + cj];
            float y = (x - mean) * rstd * gm + bt;
            y = y / (1.0f + expf(-y));
            tile[cj * 65 + ni0 + i * 8] = y;
        }
    }
    __syncthreads();
    int nj = t & 63, ci0 = t >> 6;
#pragma unroll
    for (int i = 0; i < 8; ++i) {
        int c = ci0 + i * 4;
        int n = n0 + nj;
        if (n < NN) out[(b * CC + c0 + c) * NN + n] = tile[c * 65 + nj];
    }
}

extern "C" void kernel_launch(void* const* d_in, const int* in_sizes, int n_in,
                              void* d_out, int out_size, void* d_ws, size_t ws_size,
                              hipStream_t stream) {
    const float* x      = (const float*)d_in[0];
    const float* w1     = (const float*)d_in[1];
    const float* b1     = (const float*)d_in[2];
    const float* w2     = (const float*)d_in[3];
    const float* b2     = (const float*)d_in[4];
    const float* gamma1 = (const float*)d_in[5];
    const float* beta1  = (const float*)d_in[6];
    const float* gamma2 = (const float*)d_in[7];
    const float* beta2  = (const float*)d_in[8];
    float* out = (float*)d_out;

    const int BIG = ROWS_TOTAL * CC;      // 8,294,400 floats
    float* ws   = (float*)d_ws;
    float* bufA = ws;                      // xn -> gath1 -> gemm2out
    float* bufB = ws + BIG;                // xnT -> gemm1out -> feat2 -> gath2
    float* vbuf = ws + 2 * BIG;            // [64800*9]
    int*   ibuf = (int*)(ws + 2 * BIG + ROWS_TOTAL * KK);
    float* stats = ws + 2 * BIG + 2 * ROWS_TOTAL * KK;   // [32*4*2]

    k_normalize<<<ROWS_TOTAL / 4, 256, 0, stream>>>(x, bufA, bufB);
    k_sim_topk<<<dim3((NN + RT - 1) / RT, BN), 256, 0, stream>>>(bufB, vbuf, ibuf);

    // layer 1  (xnT in bufB is dead after topk)
    k_gemm<<<(ROWS_TOTAL + 31) / 32, 256, 0, stream>>>(bufA, w1, bufB);
    k_gather<<<ROWS_TOTAL / 2, 256, 0, stream>>>(bufB, vbuf, ibuf, b1, bufA);
    k_gnstats<<<BN * NGROUP, 256, 0, stream>>>(bufA, stats);
    k_gnsilu<<<BIG / 1024, 256, 0, stream>>>(bufA, stats, gamma1, beta1, bufB);

    // layer 2
    k_gemm<<<(ROWS_TOTAL + 31) / 32, 256, 0, stream>>>(bufB, w2, bufA);
    k_gather<<<ROWS_TOTAL / 2, 256, 0, stream>>>(bufA, vbuf, ibuf, b2, bufB);
    k_gnstats<<<BN * NGROUP, 256, 0, stream>>>(bufB, stats);
    k_gnsilu_out<<<dim3((NN + 63) / 64, NGROUP, BN), 256, 0, stream>>>(bufB, stats, gamma2, beta2, out);
}

// Round 3
// 1452.019 us; speedup vs baseline: 1.3397x; 1.3397x over previous
//
#include <hip/hip_runtime.h>
#include <hip/hip_bf16.h>

#define BN 32
#define CC 128
#define NN 2025
#define KK 9
#define NGROUP 4
#define CPG 32
#define GN_EPS 1e-5f
#define ROWS_TOTAL (BN * NN)   // 64800

typedef _Float16 f16;
typedef __attribute__((ext_vector_type(8))) _Float16 f16x8;
typedef __attribute__((ext_vector_type(4))) float f32x4;

#define S28 3.725290298461914e-09f   // 2^-28
#define S40 9.094947017729282e-13f   // 2^-40
#define RH  6.103515625e-05f         // 2^-14
#define RL  1.4901161193847656e-08f  // 2^-26

// ---------------- Kernel 1: L2 normalize -> scaled f16 split, row-major [B*N][C] ----------------
__global__ __launch_bounds__(256) void k_normalize(const float* __restrict__ x,
                                                   f16* __restrict__ xh, f16* __restrict__ xl) {
    int wid  = blockIdx.x * 4 + (threadIdx.x >> 6);   // one wave per (b,n)
    int lane = threadIdx.x & 63;
    int b = wid / NN;
    int n = wid - b * NN;
    float v0 = x[(b * CC + lane) * NN + n];
    float v1 = x[(b * CC + lane + 64) * NN + n];
    float ss = v0 * v0 + v1 * v1;
#pragma unroll
    for (int off = 32; off > 0; off >>= 1) ss += __shfl_xor(ss, off);
    float s = 1.0f / fmaxf(sqrtf(ss), 1e-12f);
    v0 *= s; v1 *= s;
    float w0 = v0 * 16384.0f, w1 = v1 * 16384.0f;
    f16 h0 = (f16)w0, h1 = (f16)w1;
    f16 l0 = (f16)((w0 - (float)h0) * 4096.0f);
    f16 l1 = (f16)((w1 - (float)h1) * 4096.0f);
    size_t base = (size_t)wid * CC;
    xh[base + lane] = h0;  xh[base + lane + 64] = h1;
    xl[base + lane] = l0;  xl[base + lane + 64] = l1;
}

// top-9 insert: (value desc, index asc) ordering; caller guards validity
__device__ __forceinline__ void ins9(float cand, int m, float* v, int* ix,
                                     float& mv, int& mi, int& mp) {
    bool take = (cand > mv) || ((cand == mv) && (m < mi));
    if (take) {
#pragma unroll
        for (int k = 0; k < 9; ++k) if (k == mp) { v[k] = cand; ix[k] = m; }
        float nv = v[0]; int ni = ix[0]; int np = 0;
#pragma unroll
        for (int k = 1; k < 9; ++k) {
            if (v[k] < nv || (v[k] == nv && ix[k] > ni)) { nv = v[k]; ni = ix[k]; np = k; }
        }
        mv = nv; mi = ni; mp = np;
    }
}

// ---------------- Kernel 2: fused sim + top-k via f16-split MFMA ----------------
// Block: 32 sim-rows (2 row-tiles of 16), 4 waves with private 16-m windows.
// D[i=m][j=r] per 16x16x32 MFMA: lane jr=lane&15 -> one sim row; q=lane>>4 -> k/m quad.
__global__ __launch_bounds__(256) void k_sim_topk(const f16* __restrict__ xh, const f16* __restrict__ xl,
                                                  float* __restrict__ vout, int* __restrict__ iout) {
    __shared__ float sv[128][9];
    __shared__ int   si[128][9];

    const int b    = blockIdx.y;
    const int r0   = blockIdx.x * 32;
    const int t    = threadIdx.x;
    const int w    = t >> 6;
    const int lane = t & 63;
    const int jr   = lane & 15;
    const int q    = lane >> 4;

    // B fragments: rows r0+tile*16+jr, 4 K-steps of 32, lane's k-window = s*32 + q*8
    f16x8 bh[2][4], bl[2][4];
#pragma unroll
    for (int tile = 0; tile < 2; ++tile) {
        int rr = b * NN + min(r0 + tile * 16 + jr, NN - 1);
        const f16* pH = xh + (size_t)rr * CC;
        const f16* pL = xl + (size_t)rr * CC;
#pragma unroll
        for (int s = 0; s < 4; ++s) {
            bh[tile][s] = *(const f16x8*)(pH + s * 32 + q * 8);
            bl[tile][s] = *(const f16x8*)(pL + s * 32 + q * 8);
        }
    }

    float v9[2][9]; int i9[2][9];
    float mnv[2]; int mni[2]; int mnp[2];
#pragma unroll
    for (int tile = 0; tile < 2; ++tile) {
#pragma unroll
        for (int k = 0; k < 9; ++k) { v9[tile][k] = -3.0e38f; i9[tile][k] = 0x7fffffff; }
        mnv[tile] = -3.0e38f; mni[tile] = 0x7fffffff; mnp[tile] = 0;
    }

    for (int chunk = 0; chunk < 32; ++chunk) {
        const int mb = chunk * 64 + w * 16;                 // wave-private 16-m window
        const int marow = b * NN + min(mb + jr, NN - 1);    // A row = m-side, indexed by lane&15
        const f16* aHp = xh + (size_t)marow * CC;
        const f16* aLp = xl + (size_t)marow * CC;
        f32x4 h0 = {0.f, 0.f, 0.f, 0.f}, l0 = {0.f, 0.f, 0.f, 0.f};
        f32x4 h1 = {0.f, 0.f, 0.f, 0.f}, l1 = {0.f, 0.f, 0.f, 0.f};
#pragma unroll
        for (int s = 0; s < 4; ++s) {
            f16x8 ah = *(const f16x8*)(aHp + s * 32 + q * 8);
            f16x8 al = *(const f16x8*)(aLp + s * 32 + q * 8);
            h0 = __builtin_amdgcn_mfma_f32_16x16x32_f16(ah, bh[0][s], h0, 0, 0, 0);
            l0 = __builtin_amdgcn_mfma_f32_16x16x32_f16(ah, bl[0][s], l0, 0, 0, 0);
            l0 = __builtin_amdgcn_mfma_f32_16x16x32_f16(al, bh[0][s], l0, 0, 0, 0);
            h1 = __builtin_amdgcn_mfma_f32_16x16x32_f16(ah, bh[1][s], h1, 0, 0, 0);
            l1 = __builtin_amdgcn_mfma_f32_16x16x32_f16(ah, bl[1][s], l1, 0, 0, 0);
            l1 = __builtin_amdgcn_mfma_f32_16x16x32_f16(al, bh[1][s], l1, 0, 0, 0);
        }
        // candidates: m = mb + q*4 + reg (ascending per lane)
#pragma unroll
        for (int reg = 0; reg < 4; ++reg) {
            int m = mb + q * 4 + reg;
            if (m < NN) {
                float c0 = h0[reg] * S28 + l0[reg] * S40;
                ins9(c0, m, v9[0], i9[0], mnv[0], mni[0], mnp[0]);
                float c1 = h1[reg] * S28 + l1[reg] * S40;
                ins9(c1, m, v9[1], i9[1], mnv[1], mni[1], mnp[1]);
            }
        }
    }

    // intra-wave merge across quads: snapshot partner, then insert (xor 16, then xor 32)
#pragma unroll
    for (int tile = 0; tile < 2; ++tile) {
        float pv[9]; int pi[9];
#pragma unroll
        for (int k = 0; k < 9; ++k) { pv[k] = __shfl_xor(v9[tile][k], 16); pi[k] = __shfl_xor(i9[tile][k], 16); }
#pragma unroll
        for (int k = 0; k < 9; ++k) ins9(pv[k], pi[k], v9[tile], i9[tile], mnv[tile], mni[tile], mnp[tile]);
#pragma unroll
        for (int k = 0; k < 9; ++k) { pv[k] = __shfl_xor(v9[tile][k], 32); pi[k] = __shfl_xor(i9[tile][k], 32); }
#pragma unroll
        for (int k = 0; k < 9; ++k) ins9(pv[k], pi[k], v9[tile], i9[tile], mnv[tile], mni[tile], mnp[tile]);
    }

    // stage per-wave merged lists: lanes 0..31 write row-slot (lane>>4 selects tile)
    if (lane < 32) {
        bool useB = (lane >= 16);
#pragma unroll
        for (int k = 0; k < 9; ++k) {
            sv[w * 32 + lane][k] = useB ? v9[1][k] : v9[0][k];
            si[w * 32 + lane][k] = useB ? i9[1][k] : i9[0][k];
        }
    }
    __syncthreads();

    // cross-wave merge + output: threads 0..31 (wave 0 already holds its own lists)
    if (t < 32) {
        bool useB = (t >= 16);
        float fv[9]; int fi[9];
#pragma unroll
        for (int k = 0; k < 9; ++k) {
            fv[k] = useB ? v9[1][k] : v9[0][k];
            fi[k] = useB ? i9[1][k] : i9[0][k];
        }
        float fmv = useB ? mnv[1] : mnv[0];
        int   fmi = useB ? mni[1] : mni[0];
        int   fmp = useB ? mnp[1] : mnp[0];
        for (int ww = 1; ww < 4; ++ww) {
#pragma unroll
            for (int k = 0; k < 9; ++k) ins9(sv[ww * 32 + t][k], si[ww * 32 + t][k], fv, fi, fmv, fmi, fmp);
        }
        int r = r0 + t;
        if (r < NN) {
            float s = 1e-6f;
#pragma unroll
            for (int k = 0; k < 9; ++k) s += fv[k];
            float inv = 1.0f / s;
            int base = (b * NN + r) * KK;
#pragma unroll
            for (int k = 0; k < 9; ++k) { vout[base + k] = fv[k] * inv; iout[base + k] = fi[k]; }
        }
    }
}

// ---------------- Kernel 3a: GEMM out = reconstruct(xh,xl) @ w  (layer 1) ----------------
#define RST 36
__global__ __launch_bounds__(256) void k_gemm_hl(const f16* __restrict__ xh, const f16* __restrict__ xl,
                                                 const float* __restrict__ w, float* __restrict__ out) {
    __shared__ float rowsT[CC * RST];
    int t = threadIdx.x;
    int row0 = blockIdx.x * 32;
    for (int it = 0; it < 16; ++it) {
        int qq = t + it * 256;
        int c = qq & 127, r = qq >> 7;
        size_t idx = (size_t)(row0 + r) * CC + c;
        rowsT[c * RST + r] = (float)xh[idx] * RH + (float)xl[idx] * RL;
    }
    __syncthreads();
    int j = t & 127, half = t >> 7;
    float acc[16];
#pragma unroll
    for (int r = 0; r < 16; ++r) acc[r] = 0.0f;
    for (int c = 0; c < CC; ++c) {
        float wv = w[c * CC + j];
        const float4* ap = (const float4*)&rowsT[c * RST + half * 16];
        float4 a0 = ap[0], a1 = ap[1], a2 = ap[2], a3 = ap[3];
        acc[0]  += a0.x * wv; acc[1]  += a0.y * wv; acc[2]  += a0.z * wv; acc[3]  += a0.w * wv;
        acc[4]  += a1.x * wv; acc[5]  += a1.y * wv; acc[6]  += a1.z * wv; acc[7]  += a1.w * wv;
        acc[8]  += a2.x * wv; acc[9]  += a2.y * wv; acc[10] += a2.z * wv; acc[11] += a2.w * wv;
        acc[12] += a3.x * wv; acc[13] += a3.y * wv; acc[14] += a3.z * wv; acc[15] += a3.w * wv;
    }
#pragma unroll
    for (int r = 0; r < 16; ++r) out[(size_t)(row0 + half * 16 + r) * CC + j] = acc[r];
}

// ---------------- Kernel 3b: GEMM fp32 in (layer 2) ----------------
__global__ __launch_bounds__(256) void k_gemm(const float* __restrict__ in,
                                              const float* __restrict__ w,
                                              float* __restrict__ out) {
    __shared__ float rowsT[CC * RST];
    int t = threadIdx.x;
    int row0 = blockIdx.x * 32;
    for (int it = 0; it < 16; ++it) {
        int qq = t + it * 256;
        int c = qq & 127, r = qq >> 7;
        rowsT[c * RST + r] = in[(size_t)(row0 + r) * CC + c];
    }
    __syncthreads();
    int j = t & 127, half = t >> 7;
    float acc[16];
#pragma unroll
    for (int r = 0; r < 16; ++r) acc[r] = 0.0f;
    for (int c = 0; c < CC; ++c) {
        float wv = w[c * CC + j];
        const float4* ap = (const float4*)&rowsT[c * RST + half * 16];
        float4 a0 = ap[0], a1 = ap[1], a2 = ap[2], a3 = ap[3];
        acc[0]  += a0.x * wv; acc[1]  += a0.y * wv; acc[2]  += a0.z * wv; acc[3]  += a0.w * wv;
        acc[4]  += a1.x * wv; acc[5]  += a1.y * wv; acc[6]  += a1.z * wv; acc[7]  += a1.w * wv;
        acc[8]  += a2.x * wv; acc[9]  += a2.y * wv; acc[10] += a2.z * wv; acc[11] += a2.w * wv;
        acc[12] += a3.x * wv; acc[13] += a3.y * wv; acc[14] += a3.z * wv; acc[15] += a3.w * wv;
    }
#pragma unroll
    for (int r = 0; r < 16; ++r) out[(size_t)(row0 + half * 16 + r) * CC + j] = acc[r];
}

// ---------------- Kernel 4: gather + weighted sum + bias ----------------
__global__ __launch_bounds__(256) void k_gather(const float* __restrict__ xt,
                                                const float* __restrict__ v,
                                                const int* __restrict__ idx,
                                                const float* __restrict__ bias,
                                                float* __restrict__ out) {
    int t = threadIdx.x;
    int g = blockIdx.x * 2 + (t >> 7);
    int c = t & 127;
    if (g >= ROWS_TOTAL) return;
    int b = g / NN;
    int nb = b * NN;
    float acc = bias[c];
    int base = g * KK;
#pragma unroll
    for (int k = 0; k < KK; ++k) {
        int   ii = idx[base + k];
        float vv = v[base + k];
        acc += vv * xt[(size_t)(nb + ii) * CC + c];
    }
    out[(size_t)g * CC + c] = acc;
}

// ---------------- Kernel 5: GroupNorm stats per (b, group) ----------------
__global__ __launch_bounds__(256) void k_gnstats(const float* __restrict__ xin,
                                                 float* __restrict__ stats) {
    int bg = blockIdx.x; int b = bg >> 2; int gg = bg & 3;
    size_t base = (size_t)b * (NN * CC) + gg * CPG;
    float s1 = 0.f, s2 = 0.f;
    for (int i = threadIdx.x; i < NN * CPG; i += 256) {
        float x = xin[base + (size_t)(i >> 5) * CC + (i & 31)];
        s1 += x; s2 += x * x;
    }
#pragma unroll
    for (int off = 32; off > 0; off >>= 1) { s1 += __shfl_xor(s1, off); s2 += __shfl_xor(s2, off); }
    __shared__ float r1[4], r2[4];
    int w = threadIdx.x >> 6;
    if ((threadIdx.x & 63) == 0) { r1[w] = s1; r2[w] = s2; }
    __syncthreads();
    if (threadIdx.x == 0) {
        float a = r1[0] + r1[1] + r1[2] + r1[3];
        float qq = r2[0] + r2[1] + r2[2] + r2[3];
        const float inv = 1.0f / (float)(NN * CPG);
        float mean = a * inv;
        float var = qq * inv - mean * mean;
        stats[bg * 2]     = mean;
        stats[bg * 2 + 1] = rsqrtf(fmaxf(var, 0.f) + GN_EPS);
    }
}

// ---------------- Kernel 6: GN apply + SiLU (layout-preserving, fp32 out) ----------------
__global__ __launch_bounds__(256) void k_gnsilu(const float* __restrict__ xin,
                                                const float* __restrict__ stats,
                                                const float* __restrict__ gamma,
                                                const float* __restrict__ beta,
                                                float* __restrict__ out) {
    size_t e4 = ((size_t)blockIdx.x * 256 + threadIdx.x) * 4;
    int c0 = (int)(e4 & 127);
    int b  = (int)(e4 / (NN * CC));
    int gg = c0 >> 5;
    float mean = stats[(b * 4 + gg) * 2];
    float rstd = stats[(b * 4 + gg) * 2 + 1];
    float4 x = *(const float4*)&xin[e4];
    float g0 = gamma[c0], g1 = gamma[c0 + 1], g2 = gamma[c0 + 2], g3 = gamma[c0 + 3];
    float p0 = beta[c0],  p1 = beta[c0 + 1],  p2 = beta[c0 + 2],  p3 = beta[c0 + 3];
    float y0 = (x.x - mean) * rstd * g0 + p0;
    float y1 = (x.y - mean) * rstd * g1 + p1;
    float y2 = (x.z - mean) * rstd * g2 + p2;
    float y3 = (x.w - mean) * rstd * g3 + p3;
    float4 r;
    r.x = y0 / (1.0f + expf(-y0));
    r.y = y1 / (1.0f + expf(-y1));
    r.z = y2 / (1.0f + expf(-y2));
    r.w = y3 / (1.0f + expf(-y3));
    *(float4*)&out[e4] = r;
}

// ---------------- Kernel 7: GN apply + SiLU + transpose to [B][C][N], fp32 out ----------------
__global__ __launch_bounds__(256) void k_gnsilu_out(const float* __restrict__ xin,
                                                    const float* __restrict__ stats,
                                                    const float* __restrict__ gamma,
                                                    const float* __restrict__ beta,
                                                    float* __restrict__ out) {
    __shared__ float tile[32 * 65];
    int b = blockIdx.z, ct = blockIdx.y, nt = blockIdx.x;
    int c0 = ct * 32, n0 = nt * 64;
    int t = threadIdx.x;
    int cj = t & 31, ni0 = t >> 5;
    int gg = c0 >> 5;
    float mean = stats[(b * 4 + gg) * 2];
    float rstd = stats[(b * 4 + gg) * 2 + 1];
    float gm = gamma[c0 + cj];
    float bt = beta[c0 + cj];
#pragma unroll
    for (int i = 0; i < 8; ++i) {
        int n = n0 + ni0 + i * 8;
        if (n < NN) {
            float x = xin[((size_t)b * NN + n) * CC + c0 + cj];
            float y = (x - mean) * rstd * gm + bt;
            y = y / (1.0f + expf(-y));
            tile[cj * 65 + ni0 + i * 8] = y;
        }
    }
    __syncthreads();
    int nj = t & 63, ci0 = t >> 6;
#pragma unroll
    for (int i = 0; i < 8; ++i) {
        int c = ci0 + i * 4;
        int n = n0 + nj;
        if (n < NN) out[((size_t)b * CC + c0 + c) * NN + n] = tile[c * 65 + nj];
    }
}

extern "C" void kernel_launch(void* const* d_in, const int* in_sizes, int n_in,
                              void* d_out, int out_size, void* d_ws, size_t ws_size,
                              hipStream_t stream) {
    const float* x      = (const float*)d_in[0];
    const float* w1     = (const float*)d_in[1];
    const float* b1     = (const float*)d_in[2];
    const float* w2     = (const float*)d_in[3];
    const float* b2     = (const float*)d_in[4];
    const float* gamma1 = (const float*)d_in[5];
    const float* beta1  = (const float*)d_in[6];
    const float* gamma2 = (const float*)d_in[7];
    const float* beta2  = (const float*)d_in[8];
    float* out = (float*)d_out;

    const size_t BIG = (size_t)ROWS_TOTAL * CC;   // 8,294,400
    float* ws   = (float*)d_ws;
    float* bufB = ws;                              // gemm1out -> feat2 -> gath2
    f16*   xh   = (f16*)(ws + BIG);                // f16 split hi  [BIG halves]
    f16*   xl   = xh + BIG;                        // f16 split lo  [BIG halves]
    float* bufA = ws + BIG;                        // ALIASES xh/xl; first written by gather1
    float* vbuf = ws + 2 * BIG;                    // [64800*9]
    int*   ibuf = (int*)(ws + 2 * BIG + (size_t)ROWS_TOTAL * KK);
    float* stats = ws + 2 * BIG + 2 * (size_t)ROWS_TOTAL * KK;

    k_normalize<<<ROWS_TOTAL / 4, 256, 0, stream>>>(x, xh, xl);
    k_sim_topk<<<dim3(64, BN), 256, 0, stream>>>(xh, xl, vbuf, ibuf);

    // layer 1 (xh/xl last read by k_gemm_hl; bufA aliases them and is written after)
    k_gemm_hl<<<(ROWS_TOTAL + 31) / 32, 256, 0, stream>>>(xh, xl, w1, bufB);
    k_gather<<<ROWS_TOTAL / 2, 256, 0, stream>>>(bufB, vbuf, ibuf, b1, bufA);
    k_gnstats<<<BN * NGROUP, 256, 0, stream>>>(bufA, stats);
    k_gnsilu<<<(int)(BIG / 1024), 256, 0, stream>>>(bufA, stats, gamma1, beta1, bufB);

    // layer 2
    k_gemm<<<(ROWS_TOTAL + 31) / 32, 256, 0, stream>>>(bufB, w2, bufA);
    k_gather<<<ROWS_TOTAL / 2, 256, 0, stream>>>(bufA, vbuf, ibuf, b2, bufB);
    k_gnstats<<<BN * NGROUP, 256, 0, stream>>>(bufB, stats);
    k_gnsilu_out<<<dim3((NN + 63) / 64, NGROUP, BN), 256, 0, stream>>>(bufB, stats, gamma2, beta2, out);
}

// Round 4
// 759.788 us; speedup vs baseline: 2.5602x; 1.9111x over previous
//
#include <hip/hip_runtime.h>
#include <hip/hip_bf16.h>

#define BN 32
#define CC 128
#define NN 2025
#define KK 9
#define NGROUP 4
#define CPG 32
#define GN_EPS 1e-5f
#define ROWS_TOTAL (BN * NN)   // 64800

typedef _Float16 f16;
typedef __attribute__((ext_vector_type(8))) _Float16 f16x8;
typedef __attribute__((ext_vector_type(4))) float f32x4;

#define S28 3.725290298461914e-09f   // 2^-28
#define S40 9.094947017729282e-13f   // 2^-40
#define RH  6.103515625e-05f         // 2^-14
#define RL  1.4901161193847656e-08f  // 2^-26

#define T0F 0.17f                    // survivor threshold (9th-best ~0.23, min ~0.19)
#define CAP 128                      // per-row survivor capacity (mean ~55, max ~95)

// ---------------- Kernel 1: L2 normalize -> scaled f16 split, row-major [B*N][C] ----------------
__global__ __launch_bounds__(256) void k_normalize(const float* __restrict__ x,
                                                   f16* __restrict__ xh, f16* __restrict__ xl) {
    int wid  = blockIdx.x * 4 + (threadIdx.x >> 6);   // one wave per (b,n)
    int lane = threadIdx.x & 63;
    int b = wid / NN;
    int n = wid - b * NN;
    float v0 = x[(b * CC + lane) * NN + n];
    float v1 = x[(b * CC + lane + 64) * NN + n];
    float ss = v0 * v0 + v1 * v1;
#pragma unroll
    for (int off = 32; off > 0; off >>= 1) ss += __shfl_xor(ss, off);
    float s = 1.0f / fmaxf(sqrtf(ss), 1e-12f);
    v0 *= s; v1 *= s;
    float w0 = v0 * 16384.0f, w1 = v1 * 16384.0f;
    f16 h0 = (f16)w0, h1 = (f16)w1;
    f16 l0 = (f16)((w0 - (float)h0) * 4096.0f);
    f16 l1 = (f16)((w1 - (float)h1) * 4096.0f);
    size_t base = (size_t)wid * CC;
    xh[base + lane] = h0;  xh[base + lane + 64] = h1;
    xl[base + lane] = l0;  xl[base + lane + 64] = l1;
}

// top-9 insert: (value desc, index asc) ordering; order-independent tie rules
__device__ __forceinline__ void ins9(float cand, int m, float* v, int* ix,
                                     float& mv, int& mi, int& mp) {
    bool take = (cand > mv) || ((cand == mv) && (m < mi));
    if (take) {
#pragma unroll
        for (int k = 0; k < 9; ++k) if (k == mp) { v[k] = cand; ix[k] = m; }
        float nv = v[0]; int ni = ix[0]; int np = 0;
#pragma unroll
        for (int k = 1; k < 9; ++k) {
            if (v[k] < nv || (v[k] == nv && ix[k] > ni)) { nv = v[k]; ni = ix[k]; np = k; }
        }
        mv = nv; mi = ni; mp = np;
    }
}

// ---------------- Kernel 2: fused sim + top-k: MFMA + threshold compaction ----------------
// Block: 32 sim-rows (2 row-tiles of 16), 4 waves with private 16-m windows.
// Pass A: f16-split MFMA; candidates > T0 appended to per-row LDS buffers (exec-masked,
// no top-k maintenance in the hot loop). Pass B: exact top-9 over ~55 survivors/row.
// Fallback (count<9 or >CAP): exact full-row rescan by wave 0 — deterministic correctness.
__global__ __launch_bounds__(256) void k_sim_topk(const f16* __restrict__ xh, const f16* __restrict__ xl,
                                                  float* __restrict__ vout, int* __restrict__ iout) {
    __shared__ float sv[32][CAP];
    __shared__ int   si[32][CAP];
    __shared__ int   cnt[32];
    __shared__ int   nbad;
    __shared__ int   badrows[32];

    const int b    = blockIdx.y;
    const int r0   = blockIdx.x * 32;
    const int t    = threadIdx.x;
    const int w    = t >> 6;
    const int lane = t & 63;
    const int jr   = lane & 15;
    const int q    = lane >> 4;

    if (t < 32) cnt[t] = 0;
    if (t == 0) nbad = 0;

    // B fragments: rows r0+tile*16+jr, 4 K-steps of 32, lane's k-window = s*32 + q*8
    f16x8 bh[2][4], bl[2][4];
#pragma unroll
    for (int tile = 0; tile < 2; ++tile) {
        int rr = b * NN + min(r0 + tile * 16 + jr, NN - 1);
        const f16* pH = xh + (size_t)rr * CC;
        const f16* pL = xl + (size_t)rr * CC;
#pragma unroll
        for (int s = 0; s < 4; ++s) {
            bh[tile][s] = *(const f16x8*)(pH + s * 32 + q * 8);
            bl[tile][s] = *(const f16x8*)(pL + s * 32 + q * 8);
        }
    }
    __syncthreads();

    for (int chunk = 0; chunk < 32; ++chunk) {
        const int mb = chunk * 64 + w * 16;                 // wave-private 16-m window
        const int marow = b * NN + min(mb + jr, NN - 1);    // A row = m-side
        const f16* aHp = xh + (size_t)marow * CC;
        const f16* aLp = xl + (size_t)marow * CC;
        f32x4 h0 = {0.f, 0.f, 0.f, 0.f}, l0 = {0.f, 0.f, 0.f, 0.f};
        f32x4 h1 = {0.f, 0.f, 0.f, 0.f}, l1 = {0.f, 0.f, 0.f, 0.f};
#pragma unroll
        for (int s = 0; s < 4; ++s) {
            f16x8 ah = *(const f16x8*)(aHp + s * 32 + q * 8);
            f16x8 al = *(const f16x8*)(aLp + s * 32 + q * 8);
            h0 = __builtin_amdgcn_mfma_f32_16x16x32_f16(ah, bh[0][s], h0, 0, 0, 0);
            l0 = __builtin_amdgcn_mfma_f32_16x16x32_f16(ah, bl[0][s], l0, 0, 0, 0);
            l0 = __builtin_amdgcn_mfma_f32_16x16x32_f16(al, bh[0][s], l0, 0, 0, 0);
            h1 = __builtin_amdgcn_mfma_f32_16x16x32_f16(ah, bh[1][s], h1, 0, 0, 0);
            l1 = __builtin_amdgcn_mfma_f32_16x16x32_f16(ah, bl[1][s], l1, 0, 0, 0);
            l1 = __builtin_amdgcn_mfma_f32_16x16x32_f16(al, bh[1][s], l1, 0, 0, 0);
        }
        // threshold compaction: m = mb + q*4 + reg; exec-masked LDS append
#pragma unroll
        for (int reg = 0; reg < 4; ++reg) {
            int m = mb + q * 4 + reg;
            float c0 = h0[reg] * S28 + l0[reg] * S40;
            if (m < NN && c0 > T0F) {
                int pos = atomicAdd(&cnt[jr], 1);
                if (pos < CAP) { sv[jr][pos] = c0; si[jr][pos] = m; }
            }
            float c1 = h1[reg] * S28 + l1[reg] * S40;
            if (m < NN && c1 > T0F) {
                int pos = atomicAdd(&cnt[16 + jr], 1);
                if (pos < CAP) { sv[16 + jr][pos] = c1; si[16 + jr][pos] = m; }
            }
        }
    }
    __syncthreads();

    // Pass B: exact top-9 over survivors, one thread per row
    if (t < 32) {
        int r = r0 + t;
        if (r < NN) {
            int c = cnt[t];
            if (c >= 9 && c <= CAP) {
                float fv[9]; int fi[9];
#pragma unroll
                for (int k = 0; k < 9; ++k) { fv[k] = -3.0e38f; fi[k] = 0x7fffffff; }
                float mv = -3.0e38f; int mi = 0x7fffffff; int mp = 0;
                for (int j = 0; j < c; ++j) ins9(sv[t][j], si[t][j], fv, fi, mv, mi, mp);
                float s = 1e-6f;
#pragma unroll
                for (int k = 0; k < 9; ++k) s += fv[k];
                float inv = 1.0f / s;
                int base = (b * NN + r) * KK;
#pragma unroll
                for (int k = 0; k < 9; ++k) { vout[base + k] = fv[k] * inv; iout[base + k] = fi[k]; }
            } else {
                int slot = atomicAdd(&nbad, 1);
                badrows[slot] = r;
            }
        }
    }
    __syncthreads();

    // Fallback: wave 0 exactly re-solves any bad rows (expected: none)
    if (w == 0) {
        int nb = nbad;
        for (int ib = 0; ib < nb; ++ib) {
            int r = badrows[ib];
            const f16* rH = xh + ((size_t)b * NN + r) * CC;
            const f16* rL = xl + ((size_t)b * NN + r) * CC;
            float fv[9]; int fi[9];
#pragma unroll
            for (int k = 0; k < 9; ++k) { fv[k] = -3.0e38f; fi[k] = 0x7fffffff; }
            float mv = -3.0e38f; int mi = 0x7fffffff; int mp = 0;
            for (int m = lane; m < NN; m += 64) {
                const f16* mH = xh + ((size_t)b * NN + m) * CC;
                const f16* mL = xl + ((size_t)b * NN + m) * CC;
                float a1 = 0.f, a2 = 0.f;
                for (int c2 = 0; c2 < CC; ++c2) {
                    float hr = (float)rH[c2], hm = (float)mH[c2];
                    float lr = (float)rL[c2], lm = (float)mL[c2];
                    a1 += hr * hm;
                    a2 += hr * lm + lr * hm;
                }
                ins9(a1 * S28 + a2 * S40, m, fv, fi, mv, mi, mp);
            }
#pragma unroll
            for (int off = 1; off < 64; off <<= 1) {
                float pv[9]; int pi[9];
#pragma unroll
                for (int k = 0; k < 9; ++k) { pv[k] = __shfl_xor(fv[k], off); pi[k] = __shfl_xor(fi[k], off); }
#pragma unroll
                for (int k = 0; k < 9; ++k) ins9(pv[k], pi[k], fv, fi, mv, mi, mp);
            }
            if (lane == 0) {
                float s = 1e-6f;
#pragma unroll
                for (int k = 0; k < 9; ++k) s += fv[k];
                float inv = 1.0f / s;
                int base = (b * NN + r) * KK;
#pragma unroll
                for (int k = 0; k < 9; ++k) { vout[base + k] = fv[k] * inv; iout[base + k] = fi[k]; }
            }
        }
    }
}

// ---------------- Kernel 3a: GEMM out = reconstruct(xh,xl) @ w  (layer 1) ----------------
#define RST 36
__global__ __launch_bounds__(256) void k_gemm_hl(const f16* __restrict__ xh, const f16* __restrict__ xl,
                                                 const float* __restrict__ w, float* __restrict__ out) {
    __shared__ float rowsT[CC * RST];
    int t = threadIdx.x;
    int row0 = blockIdx.x * 32;
    for (int it = 0; it < 16; ++it) {
        int qq = t + it * 256;
        int c = qq & 127, r = qq >> 7;
        size_t idx = (size_t)(row0 + r) * CC + c;
        rowsT[c * RST + r] = (float)xh[idx] * RH + (float)xl[idx] * RL;
    }
    __syncthreads();
    int j = t & 127, half = t >> 7;
    float acc[16];
#pragma unroll
    for (int r = 0; r < 16; ++r) acc[r] = 0.0f;
    for (int c = 0; c < CC; ++c) {
        float wv = w[c * CC + j];
        const float4* ap = (const float4*)&rowsT[c * RST + half * 16];
        float4 a0 = ap[0], a1 = ap[1], a2 = ap[2], a3 = ap[3];
        acc[0]  += a0.x * wv; acc[1]  += a0.y * wv; acc[2]  += a0.z * wv; acc[3]  += a0.w * wv;
        acc[4]  += a1.x * wv; acc[5]  += a1.y * wv; acc[6]  += a1.z * wv; acc[7]  += a1.w * wv;
        acc[8]  += a2.x * wv; acc[9]  += a2.y * wv; acc[10] += a2.z * wv; acc[11] += a2.w * wv;
        acc[12] += a3.x * wv; acc[13] += a3.y * wv; acc[14] += a3.z * wv; acc[15] += a3.w * wv;
    }
#pragma unroll
    for (int r = 0; r < 16; ++r) out[(size_t)(row0 + half * 16 + r) * CC + j] = acc[r];
}

// ---------------- Kernel 3b: GEMM fp32 in (layer 2) ----------------
__global__ __launch_bounds__(256) void k_gemm(const float* __restrict__ in,
                                              const float* __restrict__ w,
                                              float* __restrict__ out) {
    __shared__ float rowsT[CC * RST];
    int t = threadIdx.x;
    int row0 = blockIdx.x * 32;
    for (int it = 0; it < 16; ++it) {
        int qq = t + it * 256;
        int c = qq & 127, r = qq >> 7;
        rowsT[c * RST + r] = in[(size_t)(row0 + r) * CC + c];
    }
    __syncthreads();
    int j = t & 127, half = t >> 7;
    float acc[16];
#pragma unroll
    for (int r = 0; r < 16; ++r) acc[r] = 0.0f;
    for (int c = 0; c < CC; ++c) {
        float wv = w[c * CC + j];
        const float4* ap = (const float4*)&rowsT[c * RST + half * 16];
        float4 a0 = ap[0], a1 = ap[1], a2 = ap[2], a3 = ap[3];
        acc[0]  += a0.x * wv; acc[1]  += a0.y * wv; acc[2]  += a0.z * wv; acc[3]  += a0.w * wv;
        acc[4]  += a1.x * wv; acc[5]  += a1.y * wv; acc[6]  += a1.z * wv; acc[7]  += a1.w * wv;
        acc[8]  += a2.x * wv; acc[9]  += a2.y * wv; acc[10] += a2.z * wv; acc[11] += a2.w * wv;
        acc[12] += a3.x * wv; acc[13] += a3.y * wv; acc[14] += a3.z * wv; acc[15] += a3.w * wv;
    }
#pragma unroll
    for (int r = 0; r < 16; ++r) out[(size_t)(row0 + half * 16 + r) * CC + j] = acc[r];
}

// ---------------- Kernel 4: gather + weighted sum + bias ----------------
__global__ __launch_bounds__(256) void k_gather(const float* __restrict__ xt,
                                                const float* __restrict__ v,
                                                const int* __restrict__ idx,
                                                const float* __restrict__ bias,
                                                float* __restrict__ out) {
    int t = threadIdx.x;
    int g = blockIdx.x * 2 + (t >> 7);
    int c = t & 127;
    if (g >= ROWS_TOTAL) return;
    int b = g / NN;
    int nb = b * NN;
    float acc = bias[c];
    int base = g * KK;
#pragma unroll
    for (int k = 0; k < KK; ++k) {
        int   ii = idx[base + k];
        float vv = v[base + k];
        acc += vv * xt[(size_t)(nb + ii) * CC + c];
    }
    out[(size_t)g * CC + c] = acc;
}

// ---------------- Kernel 5: GroupNorm stats per (b, group) ----------------
__global__ __launch_bounds__(256) void k_gnstats(const float* __restrict__ xin,
                                                 float* __restrict__ stats) {
    int bg = blockIdx.x; int b = bg >> 2; int gg = bg & 3;
    size_t base = (size_t)b * (NN * CC) + gg * CPG;
    float s1 = 0.f, s2 = 0.f;
    for (int i = threadIdx.x; i < NN * CPG; i += 256) {
        float x = xin[base + (size_t)(i >> 5) * CC + (i & 31)];
        s1 += x; s2 += x * x;
    }
#pragma unroll
    for (int off = 32; off > 0; off >>= 1) { s1 += __shfl_xor(s1, off); s2 += __shfl_xor(s2, off); }
    __shared__ float r1[4], r2[4];
    int w = threadIdx.x >> 6;
    if ((threadIdx.x & 63) == 0) { r1[w] = s1; r2[w] = s2; }
    __syncthreads();
    if (threadIdx.x == 0) {
        float a = r1[0] + r1[1] + r1[2] + r1[3];
        float qq = r2[0] + r2[1] + r2[2] + r2[3];
        const float inv = 1.0f / (float)(NN * CPG);
        float mean = a * inv;
        float var = qq * inv - mean * mean;
        stats[bg * 2]     = mean;
        stats[bg * 2 + 1] = rsqrtf(fmaxf(var, 0.f) + GN_EPS);
    }
}

// ---------------- Kernel 6: GN apply + SiLU (layout-preserving, fp32 out) ----------------
__global__ __launch_bounds__(256) void k_gnsilu(const float* __restrict__ xin,
                                                const float* __restrict__ stats,
                                                const float* __restrict__ gamma,
                                                const float* __restrict__ beta,
                                                float* __restrict__ out) {
    size_t e4 = ((size_t)blockIdx.x * 256 + threadIdx.x) * 4;
    int c0 = (int)(e4 & 127);
    int b  = (int)(e4 / (NN * CC));
    int gg = c0 >> 5;
    float mean = stats[(b * 4 + gg) * 2];
    float rstd = stats[(b * 4 + gg) * 2 + 1];
    float4 x = *(const float4*)&xin[e4];
    float g0 = gamma[c0], g1 = gamma[c0 + 1], g2 = gamma[c0 + 2], g3 = gamma[c0 + 3];
    float p0 = beta[c0],  p1 = beta[c0 + 1],  p2 = beta[c0 + 2],  p3 = beta[c0 + 3];
    float y0 = (x.x - mean) * rstd * g0 + p0;
    float y1 = (x.y - mean) * rstd * g1 + p1;
    float y2 = (x.z - mean) * rstd * g2 + p2;
    float y3 = (x.w - mean) * rstd * g3 + p3;
    float4 r;
    r.x = y0 / (1.0f + expf(-y0));
    r.y = y1 / (1.0f + expf(-y1));
    r.z = y2 / (1.0f + expf(-y2));
    r.w = y3 / (1.0f + expf(-y3));
    *(float4*)&out[e4] = r;
}

// ---------------- Kernel 7: GN apply + SiLU + transpose to [B][C][N], fp32 out ----------------
__global__ __launch_bounds__(256) void k_gnsilu_out(const float* __restrict__ xin,
                                                    const float* __restrict__ stats,
                                                    const float* __restrict__ gamma,
                                                    const float* __restrict__ beta,
                                                    float* __restrict__ out) {
    __shared__ float tile[32 * 65];
    int b = blockIdx.z, ct = blockIdx.y, nt = blockIdx.x;
    int c0 = ct * 32, n0 = nt * 64;
    int t = threadIdx.x;
    int cj = t & 31, ni0 = t >> 5;
    int gg = c0 >> 5;
    float mean = stats[(b * 4 + gg) * 2];
    float rstd = stats[(b * 4 + gg) * 2 + 1];
    float gm = gamma[c0 + cj];
    float bt = beta[c0 + cj];
#pragma unroll
    for (int i = 0; i < 8; ++i) {
        int n = n0 + ni0 + i * 8;
        if (n < NN) {
            float x = xin[((size_t)b * NN + n) * CC + c0 + cj];
            float y = (x - mean) * rstd * gm + bt;
            y = y / (1.0f + expf(-y));
            tile[cj * 65 + ni0 + i * 8] = y;
        }
    }
    __syncthreads();
    int nj = t & 63, ci0 = t >> 6;
#pragma unroll
    for (int i = 0; i < 8; ++i) {
        int c = ci0 + i * 4;
        int n = n0 + nj;
        if (n < NN) out[((size_t)b * CC + c0 + c) * NN + n] = tile[c * 65 + nj];
    }
}

extern "C" void kernel_launch(void* const* d_in, const int* in_sizes, int n_in,
                              void* d_out, int out_size, void* d_ws, size_t ws_size,
                              hipStream_t stream) {
    const float* x      = (const float*)d_in[0];
    const float* w1     = (const float*)d_in[1];
    const float* b1     = (const float*)d_in[2];
    const float* w2     = (const float*)d_in[3];
    const float* b2     = (const float*)d_in[4];
    const float* gamma1 = (const float*)d_in[5];
    const float* beta1  = (const float*)d_in[6];
    const float* gamma2 = (const float*)d_in[7];
    const float* beta2  = (const float*)d_in[8];
    float* out = (float*)d_out;

    const size_t BIG = (size_t)ROWS_TOTAL * CC;   // 8,294,400
    float* ws   = (float*)d_ws;
    float* bufB = ws;                              // gemm1out -> feat2 -> gath2
    f16*   xh   = (f16*)(ws + BIG);                // f16 split hi
    f16*   xl   = xh + BIG;                        // f16 split lo
    float* bufA = ws + BIG;                        // ALIASES xh/xl; first written by gather1
    float* vbuf = ws + 2 * BIG;                    // [64800*9]
    int*   ibuf = (int*)(ws + 2 * BIG + (size_t)ROWS_TOTAL * KK);
    float* stats = ws + 2 * BIG + 2 * (size_t)ROWS_TOTAL * KK;

    k_normalize<<<ROWS_TOTAL / 4, 256, 0, stream>>>(x, xh, xl);
    k_sim_topk<<<dim3(64, BN), 256, 0, stream>>>(xh, xl, vbuf, ibuf);

    // layer 1 (xh/xl last read by k_gemm_hl; bufA aliases them and is written after)
    k_gemm_hl<<<(ROWS_TOTAL + 31) / 32, 256, 0, stream>>>(xh, xl, w1, bufB);
    k_gather<<<ROWS_TOTAL / 2, 256, 0, stream>>>(bufB, vbuf, ibuf, b1, bufA);
    k_gnstats<<<BN * NGROUP, 256, 0, stream>>>(bufA, stats);
    k_gnsilu<<<(int)(BIG / 1024), 256, 0, stream>>>(bufA, stats, gamma1, beta1, bufB);

    // layer 2
    k_gemm<<<(ROWS_TOTAL + 31) / 32, 256, 0, stream>>>(bufB, w2, bufA);
    k_gather<<<ROWS_TOTAL / 2, 256, 0, stream>>>(bufA, vbuf, ibuf, b2, bufB);
    k_gnstats<<<BN * NGROUP, 256, 0, stream>>>(bufB, stats);
    k_gnsilu_out<<<dim3((NN + 63) / 64, NGROUP, BN), 256, 0, stream>>>(bufB, stats, gamma2, beta2, out);
}